// Round 1
// baseline (95.937 us; speedup 1.0000x reference)
//
#include <hip/hip_runtime.h>
#include <math.h>

#define Lc 2048
#define Bc 64
#define Hc 1024
#define Ac 3

// ---------------- kernel 1: ha[b,k] = sum_h hidden[b,h] * Am[h,k] ----------------
__global__ __launch_bounds__(256) void ha_kernel(const float* __restrict__ hidden,
                                                 const float* __restrict__ am,
                                                 float* __restrict__ ha) {
    int b = blockIdx.x;
    int t = threadIdx.x;
    float s0 = 0.f, s1 = 0.f, s2 = 0.f;
    for (int h = t; h < Hc; h += 256) {
        float hv = hidden[b * Hc + h];
        s0 += hv * am[h * 3 + 0];
        s1 += hv * am[h * 3 + 1];
        s2 += hv * am[h * 3 + 2];
    }
    // butterfly wave reduce (wave64)
    for (int off = 1; off < 64; off <<= 1) {
        s0 += __shfl_xor(s0, off);
        s1 += __shfl_xor(s1, off);
        s2 += __shfl_xor(s2, off);
    }
    __shared__ float red[3][4];
    int wave = t >> 6;
    if ((t & 63) == 0) { red[0][wave] = s0; red[1][wave] = s1; red[2][wave] = s2; }
    __syncthreads();
    if (t == 0) {
        ha[b * 3 + 0] = red[0][0] + red[0][1] + red[0][2] + red[0][3];
        ha[b * 3 + 1] = red[1][0] + red[1][1] + red[1][2] + red[1][3];
        ha[b * 3 + 2] = red[2][0] + red[2][1] + red[2][2] + red[2][3];
    }
}

// ---------------- kernel 2: energies[b,l] = h[b].enc[l,b,:] + ha[b].emb[l,b,:] ----
// One wave per row r = l*B + b (enc row is contiguous H floats).
__global__ __launch_bounds__(256) void energy_kernel(const float* __restrict__ hidden,
                                                     const float* __restrict__ enc,
                                                     const float* __restrict__ emb,
                                                     const float* __restrict__ ha,
                                                     float* __restrict__ energies) {
    int wave = threadIdx.x >> 6;
    int lane = threadIdx.x & 63;
    int r = blockIdx.x * 4 + wave;      // r in [0, L*B)
    int b = r & (Bc - 1);               // B = 64
    int l = r >> 6;                     // r / B

    const float4* __restrict__ erow = (const float4*)(enc + (size_t)r * Hc);
    const float4* __restrict__ hrow = (const float4*)(hidden + (size_t)b * Hc);

    float acc = 0.f;
#pragma unroll
    for (int i = 0; i < 4; ++i) {        // 4 * 64 lanes * 4 floats = 1024 = H
        float4 e  = erow[i * 64 + lane];
        float4 hv = hrow[i * 64 + lane];
        acc += e.x * hv.x + e.y * hv.y + e.z * hv.z + e.w * hv.w;
    }
    for (int off = 1; off < 64; off <<= 1) acc += __shfl_xor(acc, off);

    if (lane == 0) {
        const float* em = emb + (size_t)r * 3;
        const float* hb = ha + (size_t)b * 3;
        float aff = hb[0] * em[0] + hb[1] * em[1] + hb[2] * em[2];
        energies[(size_t)b * Lc + l] = acc + aff;
    }
}

// ---------------- kernel 3: row softmax over L, write [B,1,L] f32 -----------------
__global__ __launch_bounds__(256) void softmax_kernel(const float* __restrict__ energies,
                                                      float* __restrict__ out) {
    int b = blockIdx.x;
    int t = threadIdx.x;
    const float* row = energies + (size_t)b * Lc;

    float vals[8];
    float m = -INFINITY;
#pragma unroll
    for (int i = 0; i < 8; ++i) {        // 8 * 256 = 2048 = L
        vals[i] = row[t + i * 256];
        m = fmaxf(m, vals[i]);
    }
    __shared__ float sred[4];
    for (int off = 1; off < 64; off <<= 1) m = fmaxf(m, __shfl_xor(m, off));
    int wave = t >> 6;
    if ((t & 63) == 0) sred[wave] = m;
    __syncthreads();
    m = fmaxf(fmaxf(sred[0], sred[1]), fmaxf(sred[2], sred[3]));
    __syncthreads();

    float s = 0.f;
#pragma unroll
    for (int i = 0; i < 8; ++i) {
        vals[i] = __expf(vals[i] - m);
        s += vals[i];
    }
    for (int off = 1; off < 64; off <<= 1) s += __shfl_xor(s, off);
    if ((t & 63) == 0) sred[wave] = s;
    __syncthreads();
    s = sred[0] + sred[1] + sred[2] + sred[3];
    float inv = 1.0f / s;

#pragma unroll
    for (int i = 0; i < 8; ++i) out[(size_t)b * Lc + t + i * 256] = vals[i] * inv;
}

extern "C" void kernel_launch(void* const* d_in, const int* in_sizes, int n_in,
                              void* d_out, int out_size, void* d_ws, size_t ws_size,
                              hipStream_t stream) {
    const float* hidden = (const float*)d_in[0];   // [1,B,H]
    const float* enc    = (const float*)d_in[1];   // [L,B,H]
    const float* emb    = (const float*)d_in[2];   // [L,B,A]
    const float* am     = (const float*)d_in[3];   // [H,A]
    float* out = (float*)d_out;                    // [B,1,L]

    float* ha       = (float*)d_ws;                        // B*3 floats
    float* energies = (float*)d_ws + 256;                  // B*L floats (1 KiB offset)

    ha_kernel<<<Bc, 256, 0, stream>>>(hidden, am, ha);
    energy_kernel<<<(Lc * Bc) / 4, 256, 0, stream>>>(hidden, enc, emb, ha, energies);
    softmax_kernel<<<Bc, 256, 0, stream>>>(energies, out);
}